// Round 10
// baseline (278.277 us; speedup 1.0000x reference)
//
#include <hip/hip_runtime.h>
#include <hip/hip_bf16.h>
#include <cstddef>
#include <cstdint>

// NonLocal block, MI355X. Round 10 (resubmit: rounds 8/9 never executed due
// to GPU acquisition timeouts): kB with ZERO cross-lane P movement.
// S-tile0 computes even n-rows, S-tile1 odd n-rows; v_cvt_pk_bf16_f32
// interleaves them in-lane into the PV B-fragment (no LDS, no barrier,
// no memory clobber -> compiler free to software-pipeline). kA/kB use
// XCD-clustered 1-D grids (id&7 = batch) for per-XCD L2 locality.

namespace {
constexpr int kBt  = 8;
constexpr int kC   = 256;
constexpr int kCi  = 32;
constexpr int kN   = 4096;           // H*W
constexpr int kRowsT = kBt * kN;     // 32768
constexpr int kMCH = 4;              // m-chunks in kA
constexpr int kNCH = 4;              // n-chunks in kB
constexpr float kLog2e = 1.4426950408889634f;

typedef __attribute__((ext_vector_type(8))) short short8;
typedef __attribute__((ext_vector_type(4))) float f32x4;
}

__device__ __forceinline__ float fast_exp2(float x) { return __builtin_amdgcn_exp2f(x); }
__device__ __forceinline__ float fast_rcp(float x)  { return __builtin_amdgcn_rcpf(x); }
__device__ __forceinline__ float silu(float t) {
    return t * fast_rcp(1.f + fast_exp2(-t * kLog2e));
}
__device__ __forceinline__ unsigned short f2bf(float f) {
    union { float f; uint32_t u; } v; v.f = f;
    return (unsigned short)((v.u + 0x7FFFu + ((v.u >> 16) & 1u)) >> 16);
}
__device__ __forceinline__ float bf2f(unsigned short u) {
    union { uint32_t u; float f; } v; v.u = ((uint32_t)u) << 16;
    return v.f;
}
// packed bf16 convert: lo = src0, hi = src1 (single VOP3)
__device__ __forceinline__ unsigned int cvt_pk_bf16(float lo, float hi) {
    unsigned int r;
    asm("v_cvt_pk_bf16_f32 %0, %1, %2" : "=v"(r) : "v"(lo), "v"(hi));
    return r;
}

// ---------------------------------------------------------------------------
// K0: pack weights into MFMA A-fragment order (scale folded in).
// ---------------------------------------------------------------------------
__global__ __launch_bounds__(64) void k0_pack(
    const float* __restrict__ w1, const float* __restrict__ s1,
    const float* __restrict__ w2, const float* __restrict__ s2,
    const float* __restrict__ w3, const float* __restrict__ s3,
    const float* __restrict__ w4, const float* __restrict__ s4,
    short8* __restrict__ wfA, short8* __restrict__ w4f)
{
    const int l = threadIdx.x;
    const int bid = blockIdx.x;
    short8 v;
    if (bid < 48) {
        int ot = bid >> 3, kt = bid & 7;
        int p  = ot >> 1;
        int ocp = (ot & 1) * 16 + (l & 15);
        int k0  = kt * 32 + (l >> 4) * 8;
        const float* wp = (p == 0) ? w1 : (p == 1) ? w2 : w3;
        const float* sp = (p == 0) ? s1 : (p == 1) ? s2 : s3;
        float s = sp[ocp];
        #pragma unroll
        for (int e = 0; e < 8; ++e)
            v[e] = (short)f2bf(wp[ocp * kC + k0 + e] * s);
        wfA[bid * 64 + l] = v;
    } else {
        int ot = bid - 48;
        int oc = ot * 16 + (l & 15);
        int k0 = (l >> 4) * 8;
        float s = s4[oc];
        #pragma unroll
        for (int e = 0; e < 8; ++e)
            v[e] = (short)f2bf(w4[oc * kCi + k0 + e] * s);
        w4f[ot * 64 + l] = v;
    }
}

// ---------------------------------------------------------------------------
// K1: projections via MFMA (unchanged, validated).
// ---------------------------------------------------------------------------
__global__ __launch_bounds__(256) void k1_mfma(
    const float* __restrict__ x, const short8* __restrict__ wfA,
    const float* __restrict__ b1, const float* __restrict__ b2,
    const float* __restrict__ b3,
    unsigned short* __restrict__ y1t, unsigned short* __restrict__ y2t,
    unsigned short* __restrict__ y3t)
{
    const int l  = threadIdx.x & 63;
    const int w  = threadIdx.x >> 6;
    const int b  = blockIdx.x >> 6;
    const int n0 = (blockIdx.x & 63) * 64 + w * 16;
    const int px = l & 15, g = l >> 4;

    const float* xb = x + (size_t)b * kC * kN + n0 + px;

    f32x4 acc[6];
    #pragma unroll
    for (int ot = 0; ot < 6; ++ot) acc[ot] = (f32x4){0.f, 0.f, 0.f, 0.f};

    #pragma unroll
    for (int kt = 0; kt < 8; ++kt) {
        const float* xc = xb + (size_t)(kt * 32 + g * 8) * kN;
        float f[8];
        #pragma unroll
        for (int e = 0; e < 8; ++e) f[e] = xc[(size_t)e * kN];
        short8 Bf;
        #pragma unroll
        for (int e = 0; e < 8; ++e) Bf[e] = (short)f2bf(f[e]);
        #pragma unroll
        for (int ot = 0; ot < 6; ++ot)
            acc[ot] = __builtin_amdgcn_mfma_f32_16x16x32_bf16(
                wfA[(ot * 8 + kt) * 64 + l], Bf, acc[ot], 0, 0, 0);
    }

    const size_t rowbase = ((size_t)(b * kN) + n0 + px) * kCi;
    #pragma unroll
    for (int pp = 0; pp < 3; ++pp) {
        const float* bp = (pp == 0) ? b1 : (pp == 1) ? b2 : b3;
        unsigned short* yp = (pp == 0) ? y1t : (pp == 1) ? y2t : y3t;
        const float mul = (pp == 1) ? kLog2e : 1.0f;
        #pragma unroll
        for (int h = 0; h < 2; ++h) {
            int ot = pp * 2 + h;
            int oc0 = h * 16 + 4 * g;
            unsigned int wd[2];
            #pragma unroll
            for (int j2 = 0; j2 < 2; ++j2) {
                float v0 = silu(acc[ot][2 * j2]     + bp[oc0 + 2 * j2])     * mul;
                float v1 = silu(acc[ot][2 * j2 + 1] + bp[oc0 + 2 * j2 + 1]) * mul;
                wd[j2] = (unsigned)f2bf(v0) | ((unsigned)f2bf(v1) << 16);
            }
            *(uint2*)(yp + rowbase + oc0) = make_uint2(wd[0], wd[1]);
        }
    }
}

// ---------------------------------------------------------------------------
// KA: partial softmax denominators. 1-D grid 2048, id&7 = batch (XCD L2).
// ---------------------------------------------------------------------------
__global__ __launch_bounds__(256) void kA_stats(
    const unsigned short* __restrict__ y1t, const unsigned short* __restrict__ y2t,
    float* __restrict__ psum)
{
    const int l   = threadIdx.x & 63;
    const int w   = __builtin_amdgcn_readfirstlane(threadIdx.x >> 6);
    const int id  = blockIdx.x;
    const int b   = id & 7;
    const int jj  = id >> 3;          // 0..255
    const int n0  = (jj & 63) * 64;   // n-tile
    const int mch = jj >> 6;          // m-chunk 0..3
    const int m0  = mch * (kN / kMCH);
    const int r16 = l & 15, g = l >> 4;

    const short8 Af = *(const short8*)(
        y2t + ((size_t)(b * kN + n0 + w * 16 + r16) * kCi + g * 8));
    const unsigned short* y1b =
        y1t + ((size_t)b * kN + m0 + r16) * kCi + g * 8;

    float s0 = 0.f, s1 = 0.f, s2 = 0.f, s3 = 0.f;
    #pragma unroll 4
    for (int mt = 0; mt < kN / kMCH / 16; ++mt) {
        short8 Bf = *(const short8*)(y1b + (size_t)mt * 16 * kCi);
        f32x4 z = {0.f, 0.f, 0.f, 0.f};
        f32x4 S = __builtin_amdgcn_mfma_f32_16x16x32_bf16(Af, Bf, z, 0, 0, 0);
        s0 += fast_exp2(S[0]);
        s1 += fast_exp2(S[1]);
        s2 += fast_exp2(S[2]);
        s3 += fast_exp2(S[3]);
    }
    #pragma unroll
    for (int d = 1; d < 16; d <<= 1) {
        s0 += __shfl_xor(s0, d);
        s1 += __shfl_xor(s1, d);
        s2 += __shfl_xor(s2, d);
        s3 += __shfl_xor(s3, d);
    }
    if (r16 == 0) {
        float* dst = psum + (size_t)mch * kRowsT + (size_t)b * kN
                   + n0 + w * 16 + 4 * g;
        dst[0] = s0; dst[1] = s1; dst[2] = s2; dst[3] = s3;
    }
}

// ---------------------------------------------------------------------------
// KA2: combine psum chunks -> rcp -> v3T[b][c][n] = y3[n][c]/sumexp[n].
// ---------------------------------------------------------------------------
__global__ __launch_bounds__(256) void kA2_v3(
    const float* __restrict__ psum, const unsigned short* __restrict__ y3t,
    unsigned short* __restrict__ v3T)
{
    const int b  = blockIdx.x >> 6;
    const int n0 = (blockIdx.x & 63) * 64;
    __shared__ float rsum[64];
    const int t = threadIdx.x;
    if (t < 64) {
        size_t idx = (size_t)b * kN + n0 + t;
        float s = psum[idx];
        #pragma unroll
        for (int ch = 1; ch < kMCH; ++ch) s += psum[(size_t)ch * kRowsT + idx];
        rsum[t] = fast_rcp(s);
    }
    __syncthreads();

    const int c = t >> 3, q = t & 7;
    float rin[8];
    #pragma unroll
    for (int u = 0; u < 8; ++u) rin[u] = rsum[q * 8 + u];
    unsigned int wds[4];
    #pragma unroll
    for (int u = 0; u < 4; ++u) {
        float a0 = bf2f(y3t[(size_t)(b * kN + n0 + q * 8 + 2 * u) * kCi + c]) * rin[2 * u];
        float a1 = bf2f(y3t[(size_t)(b * kN + n0 + q * 8 + 2 * u + 1) * kCi + c]) * rin[2 * u + 1];
        wds[u] = (unsigned)f2bf(a0) | ((unsigned)f2bf(a1) << 16);
    }
    *(uint4*)(v3T + ((size_t)(b * kCi + c) * kN + n0 + q * 8)) =
        make_uint4(wds[0], wds[1], wds[2], wds[3]);
}

// ---------------------------------------------------------------------------
// KB: PV pass, n-chunked, LDS-free. 1-D grid 2048, id&7 = batch (XCD L2).
// S-tile0 = even n-rows, S-tile1 = odd n-rows of the 32-n chunk; element e
// of lane (r16,g)'s PV B-frag is n = nb+8g+e = interleave(S0[e/2],S1[e/2]).
// ---------------------------------------------------------------------------
__global__ __launch_bounds__(256) void kB_pv(
    const unsigned short* __restrict__ y1t, const unsigned short* __restrict__ y2t,
    const unsigned short* __restrict__ v3T, float* __restrict__ pacc)
{
    const int l   = threadIdx.x & 63;
    const int w   = threadIdx.x >> 6;
    const int id  = blockIdx.x;
    const int b   = id & 7;
    const int jj  = id >> 3;          // 0..255
    const int mt  = jj & 63;          // m-tile
    const int nch = jj >> 6;          // n-chunk 0..3
    const int m0  = mt * 64 + w * 16;
    const int n0c = nch * (kN / kNCH);
    const int r16 = l & 15, g = l >> 4;

    const short8 B1 = *(const short8*)(
        y1t + ((size_t)(b * kN + m0 + r16) * kCi + g * 8));
    // A-frag row r16 -> even n (tile0) / odd n (tile1) of each 32-n chunk
    const unsigned short* y2e =
        y2t + ((size_t)b * kN + n0c + 2 * r16) * kCi + g * 8;
    const unsigned short* y2o = y2e + kCi;
    const unsigned short* v3b =
        v3T + ((size_t)(b * kCi) + r16) * kN + n0c + g * 8;

    f32x4 acc0 = {0.f, 0.f, 0.f, 0.f};   // c = 4g+j
    f32x4 acc1 = {0.f, 0.f, 0.f, 0.f};   // c = 16+4g+j
    const f32x4 z = {0.f, 0.f, 0.f, 0.f};

    #pragma unroll 4
    for (int nt = 0; nt < kN / kNCH / 32; ++nt) {
        const size_t nb = (size_t)nt * 32;
        // S0 row r -> n = nb+2r ; S1 row r -> n = nb+2r+1 (cols = m0+r16..)
        short8 A2a = *(const short8*)(y2e + nb * kCi);
        short8 A2b = *(const short8*)(y2o + nb * kCi);
        f32x4 S0 = __builtin_amdgcn_mfma_f32_16x16x32_bf16(A2a, B1, z, 0, 0, 0);
        f32x4 S1 = __builtin_amdgcn_mfma_f32_16x16x32_bf16(A2b, B1, z, 0, 0, 0);

        // D-reg j of S0 = row 4g+j -> n = nb+8g+2j; of S1 -> n = nb+8g+2j+1.
        // B-frag word j = {P(nb+8g+2j), P(nb+8g+2j+1)} = {2^S0[j], 2^S1[j]}.
        union { unsigned int u[4]; short8 s; } bp;
        bp.u[0] = cvt_pk_bf16(fast_exp2(S0[0]), fast_exp2(S1[0]));
        bp.u[1] = cvt_pk_bf16(fast_exp2(S0[1]), fast_exp2(S1[1]));
        bp.u[2] = cvt_pk_bf16(fast_exp2(S0[2]), fast_exp2(S1[2]));
        bp.u[3] = cvt_pk_bf16(fast_exp2(S0[3]), fast_exp2(S1[3]));

        // PV A-frags: v3 rows c=r16 / c=16+r16, k = n = nb+8g..+7 (16B load)
        short8 A3a = *(const short8*)(v3b + nb);
        short8 A3b = *(const short8*)(v3b + 16 * (size_t)kN + nb);

        acc0 = __builtin_amdgcn_mfma_f32_16x16x32_bf16(A3a, bp.s, acc0, 0, 0, 0);
        acc1 = __builtin_amdgcn_mfma_f32_16x16x32_bf16(A3b, bp.s, acc1, 0, 0, 0);
    }

    float* outp = pacc + ((size_t)nch * kRowsT + (size_t)(b * kN) + m0 + r16) * kCi
                + 4 * g;
    *(float4*)(outp)      = make_float4(acc0[0], acc0[1], acc0[2], acc0[3]);
    *(float4*)(outp + 16) = make_float4(acc1[0], acc1[1], acc1[2], acc1[3]);
}

// ---------------------------------------------------------------------------
// KB2: sum the kNCH partial accumulators -> bf16 ylt rows.
// ---------------------------------------------------------------------------
__global__ __launch_bounds__(256) void kB2_reduce(
    const float* __restrict__ pacc, unsigned short* __restrict__ yltb)
{
    const size_t i = (size_t)blockIdx.x * 256 + threadIdx.x;   // float4 index
    const float4* src = reinterpret_cast<const float4*>(pacc);
    float4 s = src[i];
    #pragma unroll
    for (int ch = 1; ch < kNCH; ++ch) {
        float4 v = src[(size_t)ch * ((size_t)kRowsT * kCi / 4) + i];
        s.x += v.x; s.y += v.y; s.z += v.z; s.w += v.w;
    }
    uint2 o;
    o.x = (unsigned)f2bf(s.x) | ((unsigned)f2bf(s.y) << 16);
    o.y = (unsigned)f2bf(s.z) | ((unsigned)f2bf(s.w) << 16);
    *(uint2*)(yltb + 4 * i) = o;
}

// ---------------------------------------------------------------------------
// K4: final conv (32->256) + SiLU + residual. Wave = 16 px x 64 oc.
// ---------------------------------------------------------------------------
__global__ __launch_bounds__(256) void k4_mfma(
    const unsigned short* __restrict__ ylt, const short8* __restrict__ w4f,
    const float* __restrict__ b4, const float* __restrict__ x,
    float* __restrict__ out)
{
    const int l  = threadIdx.x & 63;
    const int w  = threadIdx.x >> 6;
    const int b  = blockIdx.x >> 8;
    const int n0 = (blockIdx.x & 255) * 16;
    const int px = l & 15, g = l >> 4;

    const short8 Bf = *(const short8*)(
        ylt + ((size_t)(b * kN) + n0 + px) * kCi + g * 8);

    f32x4 acc[4];
    #pragma unroll
    for (int u = 0; u < 4; ++u) {
        f32x4 z = {0.f, 0.f, 0.f, 0.f};
        acc[u] = __builtin_amdgcn_mfma_f32_16x16x32_bf16(
            w4f[(w * 4 + u) * 64 + l], Bf, z, 0, 0, 0);
    }

    const size_t pxg = (size_t)b * kC * kN + n0 + px;   // + oc*kN
    #pragma unroll
    for (int u = 0; u < 4; ++u) {
        const int oc0 = (w * 4 + u) * 16 + 4 * g;
        float4 bb = *(const float4*)(b4 + oc0);
        const float bbv[4] = {bb.x, bb.y, bb.z, bb.w};
        #pragma unroll
        for (int j = 0; j < 4; ++j) {
            const size_t idx = pxg + (size_t)(oc0 + j) * kN;
            float t = acc[u][j] + bbv[j];
            out[idx] = silu(t) + x[idx];
        }
    }
}

// ---------------------------------------------------------------------------
extern "C" void kernel_launch(void* const* d_in, const int* in_sizes, int n_in,
                              void* d_out, int out_size, void* d_ws, size_t ws_size,
                              hipStream_t stream)
{
    (void)in_sizes; (void)n_in; (void)out_size; (void)ws_size;
    const float* x  = (const float*)d_in[0];
    const float* w1 = (const float*)d_in[1];
    const float* s1 = (const float*)d_in[2];
    const float* b1 = (const float*)d_in[3];
    const float* w2 = (const float*)d_in[4];
    const float* s2 = (const float*)d_in[5];
    const float* b2 = (const float*)d_in[6];
    const float* w3 = (const float*)d_in[7];
    const float* s3 = (const float*)d_in[8];
    const float* b3 = (const float*)d_in[9];
    const float* w4 = (const float*)d_in[10];
    const float* s4 = (const float*)d_in[11];
    const float* b4 = (const float*)d_in[12];
    float* out = (float*)d_out;

    unsigned char* ws = (unsigned char*)d_ws;
    size_t off = 0;
    unsigned short* y1t = (unsigned short*)(ws + off); off += (size_t)kRowsT * kCi * 2;
    unsigned short* y2t = (unsigned short*)(ws + off); off += (size_t)kRowsT * kCi * 2;
    unsigned short* y3t = (unsigned short*)(ws + off); off += (size_t)kRowsT * kCi * 2;
    unsigned short* v3T = (unsigned short*)(ws + off); off += (size_t)kRowsT * kCi * 2;
    unsigned short* yltb= (unsigned short*)(ws + off); off += (size_t)kRowsT * kCi * 2;
    short8* wfA = (short8*)(ws + off); off += 48 * 64 * sizeof(short8);
    short8* w4f = (short8*)(ws + off); off += 16 * 64 * sizeof(short8);
    float* psum = (float*)(ws + off); off += (size_t)kMCH * kRowsT * 4;
    float* pacc = (float*)(ws + off); off += (size_t)kNCH * kRowsT * kCi * 4;

    k0_pack<<<dim3(64), dim3(64), 0, stream>>>(
        w1, s1, w2, s2, w3, s3, w4, s4, wfA, w4f);
    k1_mfma<<<dim3(kRowsT / 64), dim3(256), 0, stream>>>(
        x, wfA, b1, b2, b3, y1t, y2t, y3t);
    kA_stats<<<dim3(kBt * (kN / 64) * kMCH), dim3(256), 0, stream>>>(
        y1t, y2t, psum);                          // 2048 blocks
    kA2_v3<<<dim3(kBt * (kN / 64)), dim3(256), 0, stream>>>(psum, y3t, v3T);
    kB_pv<<<dim3(kBt * (kN / 64) * kNCH), dim3(256), 0, stream>>>(
        y1t, y2t, v3T, pacc);                     // 2048 blocks
    kB2_reduce<<<dim3((kRowsT * kCi / 4) / 256), dim3(256), 0, stream>>>(
        pacc, yltb);
    k4_mfma<<<dim3(kRowsT / 16), dim3(256), 0, stream>>>(
        yltb, w4f, b4, x, out);
}

// Round 11
// 275.536 us; speedup vs baseline: 1.0099x; 1.0099x over previous
//
#include <hip/hip_runtime.h>
#include <hip/hip_bf16.h>
#include <cstddef>
#include <cstdint>

// NonLocal block, MI355X. Round 11: manual software-pipelining for kA/kB.
// Round-10 post-mortem: kB was latency-bound (~1100 cyc/iter, VGPR=60 ->
// compiler issued loads right before use, stalling on waitcnt each iter).
// Fix: prefetch next iteration's fragments into named registers before the
// current iteration's compute (+ unroll 2), hiding L2 latency under the
// MFMA->exp2->cvt_pk->MFMA chain. Everything else unchanged (validated).

namespace {
constexpr int kBt  = 8;
constexpr int kC   = 256;
constexpr int kCi  = 32;
constexpr int kN   = 4096;           // H*W
constexpr int kRowsT = kBt * kN;     // 32768
constexpr int kMCH = 4;              // m-chunks in kA
constexpr int kNCH = 4;              // n-chunks in kB
constexpr float kLog2e = 1.4426950408889634f;

typedef __attribute__((ext_vector_type(8))) short short8;
typedef __attribute__((ext_vector_type(4))) float f32x4;
}

__device__ __forceinline__ float fast_exp2(float x) { return __builtin_amdgcn_exp2f(x); }
__device__ __forceinline__ float fast_rcp(float x)  { return __builtin_amdgcn_rcpf(x); }
__device__ __forceinline__ float silu(float t) {
    return t * fast_rcp(1.f + fast_exp2(-t * kLog2e));
}
__device__ __forceinline__ unsigned short f2bf(float f) {
    union { float f; uint32_t u; } v; v.f = f;
    return (unsigned short)((v.u + 0x7FFFu + ((v.u >> 16) & 1u)) >> 16);
}
__device__ __forceinline__ float bf2f(unsigned short u) {
    union { uint32_t u; float f; } v; v.u = ((uint32_t)u) << 16;
    return v.f;
}
// packed bf16 convert: lo = src0, hi = src1 (single VOP3)
__device__ __forceinline__ unsigned int cvt_pk_bf16(float lo, float hi) {
    unsigned int r;
    asm("v_cvt_pk_bf16_f32 %0, %1, %2" : "=v"(r) : "v"(lo), "v"(hi));
    return r;
}

// ---------------------------------------------------------------------------
// K0: pack weights into MFMA A-fragment order (scale folded in).
// ---------------------------------------------------------------------------
__global__ __launch_bounds__(64) void k0_pack(
    const float* __restrict__ w1, const float* __restrict__ s1,
    const float* __restrict__ w2, const float* __restrict__ s2,
    const float* __restrict__ w3, const float* __restrict__ s3,
    const float* __restrict__ w4, const float* __restrict__ s4,
    short8* __restrict__ wfA, short8* __restrict__ w4f)
{
    const int l = threadIdx.x;
    const int bid = blockIdx.x;
    short8 v;
    if (bid < 48) {
        int ot = bid >> 3, kt = bid & 7;
        int p  = ot >> 1;
        int ocp = (ot & 1) * 16 + (l & 15);
        int k0  = kt * 32 + (l >> 4) * 8;
        const float* wp = (p == 0) ? w1 : (p == 1) ? w2 : w3;
        const float* sp = (p == 0) ? s1 : (p == 1) ? s2 : s3;
        float s = sp[ocp];
        #pragma unroll
        for (int e = 0; e < 8; ++e)
            v[e] = (short)f2bf(wp[ocp * kC + k0 + e] * s);
        wfA[bid * 64 + l] = v;
    } else {
        int ot = bid - 48;
        int oc = ot * 16 + (l & 15);
        int k0 = (l >> 4) * 8;
        float s = s4[oc];
        #pragma unroll
        for (int e = 0; e < 8; ++e)
            v[e] = (short)f2bf(w4[oc * kCi + k0 + e] * s);
        w4f[ot * 64 + l] = v;
    }
}

// ---------------------------------------------------------------------------
// K1: projections via MFMA (unchanged, validated).
// ---------------------------------------------------------------------------
__global__ __launch_bounds__(256) void k1_mfma(
    const float* __restrict__ x, const short8* __restrict__ wfA,
    const float* __restrict__ b1, const float* __restrict__ b2,
    const float* __restrict__ b3,
    unsigned short* __restrict__ y1t, unsigned short* __restrict__ y2t,
    unsigned short* __restrict__ y3t)
{
    const int l  = threadIdx.x & 63;
    const int w  = threadIdx.x >> 6;
    const int b  = blockIdx.x >> 6;
    const int n0 = (blockIdx.x & 63) * 64 + w * 16;
    const int px = l & 15, g = l >> 4;

    const float* xb = x + (size_t)b * kC * kN + n0 + px;

    f32x4 acc[6];
    #pragma unroll
    for (int ot = 0; ot < 6; ++ot) acc[ot] = (f32x4){0.f, 0.f, 0.f, 0.f};

    #pragma unroll
    for (int kt = 0; kt < 8; ++kt) {
        const float* xc = xb + (size_t)(kt * 32 + g * 8) * kN;
        float f[8];
        #pragma unroll
        for (int e = 0; e < 8; ++e) f[e] = xc[(size_t)e * kN];
        short8 Bf;
        #pragma unroll
        for (int e = 0; e < 8; ++e) Bf[e] = (short)f2bf(f[e]);
        #pragma unroll
        for (int ot = 0; ot < 6; ++ot)
            acc[ot] = __builtin_amdgcn_mfma_f32_16x16x32_bf16(
                wfA[(ot * 8 + kt) * 64 + l], Bf, acc[ot], 0, 0, 0);
    }

    const size_t rowbase = ((size_t)(b * kN) + n0 + px) * kCi;
    #pragma unroll
    for (int pp = 0; pp < 3; ++pp) {
        const float* bp = (pp == 0) ? b1 : (pp == 1) ? b2 : b3;
        unsigned short* yp = (pp == 0) ? y1t : (pp == 1) ? y2t : y3t;
        const float mul = (pp == 1) ? kLog2e : 1.0f;
        #pragma unroll
        for (int h = 0; h < 2; ++h) {
            int ot = pp * 2 + h;
            int oc0 = h * 16 + 4 * g;
            unsigned int wd[2];
            #pragma unroll
            for (int j2 = 0; j2 < 2; ++j2) {
                float v0 = silu(acc[ot][2 * j2]     + bp[oc0 + 2 * j2])     * mul;
                float v1 = silu(acc[ot][2 * j2 + 1] + bp[oc0 + 2 * j2 + 1]) * mul;
                wd[j2] = (unsigned)f2bf(v0) | ((unsigned)f2bf(v1) << 16);
            }
            *(uint2*)(yp + rowbase + oc0) = make_uint2(wd[0], wd[1]);
        }
    }
}

// ---------------------------------------------------------------------------
// KA: partial softmax denominators. 1-D grid 2048, id&7 = batch (XCD L2).
// Manual 2-wide unroll + 2-ahead register prefetch (latency hiding).
// ---------------------------------------------------------------------------
__global__ __launch_bounds__(256) void kA_stats(
    const unsigned short* __restrict__ y1t, const unsigned short* __restrict__ y2t,
    float* __restrict__ psum)
{
    const int l   = threadIdx.x & 63;
    const int w   = __builtin_amdgcn_readfirstlane(threadIdx.x >> 6);
    const int id  = blockIdx.x;
    const int b   = id & 7;
    const int jj  = id >> 3;          // 0..255
    const int n0  = (jj & 63) * 64;   // n-tile
    const int mch = jj >> 6;          // m-chunk 0..3
    const int m0  = mch * (kN / kMCH);
    const int r16 = l & 15, g = l >> 4;

    const short8 Af = *(const short8*)(
        y2t + ((size_t)(b * kN + n0 + w * 16 + r16) * kCi + g * 8));
    const unsigned short* y1b =
        y1t + ((size_t)b * kN + m0 + r16) * kCi + g * 8;

    constexpr int NT = kN / kMCH / 16;   // 64 m-steps
    const f32x4 z = {0.f, 0.f, 0.f, 0.f};

    short8 Bf0 = *(const short8*)(y1b);
    short8 Bf1 = *(const short8*)(y1b + (size_t)16 * kCi);

    float s0 = 0.f, s1 = 0.f, s2 = 0.f, s3 = 0.f;
    #pragma unroll 2
    for (int mt = 0; mt < NT; mt += 2) {
        const int nx = (mt + 2 < NT) ? mt + 2 : mt;   // clamp tail
        short8 nB0 = *(const short8*)(y1b + (size_t)nx * 16 * kCi);
        short8 nB1 = *(const short8*)(y1b + (size_t)(nx + 1) * 16 * kCi);

        f32x4 Sa = __builtin_amdgcn_mfma_f32_16x16x32_bf16(Af, Bf0, z, 0, 0, 0);
        f32x4 Sb = __builtin_amdgcn_mfma_f32_16x16x32_bf16(Af, Bf1, z, 0, 0, 0);
        s0 += fast_exp2(Sa[0]) + fast_exp2(Sb[0]);
        s1 += fast_exp2(Sa[1]) + fast_exp2(Sb[1]);
        s2 += fast_exp2(Sa[2]) + fast_exp2(Sb[2]);
        s3 += fast_exp2(Sa[3]) + fast_exp2(Sb[3]);

        Bf0 = nB0; Bf1 = nB1;
    }
    #pragma unroll
    for (int d = 1; d < 16; d <<= 1) {
        s0 += __shfl_xor(s0, d);
        s1 += __shfl_xor(s1, d);
        s2 += __shfl_xor(s2, d);
        s3 += __shfl_xor(s3, d);
    }
    if (r16 == 0) {
        float* dst = psum + (size_t)mch * kRowsT + (size_t)b * kN
                   + n0 + w * 16 + 4 * g;
        dst[0] = s0; dst[1] = s1; dst[2] = s2; dst[3] = s3;
    }
}

// ---------------------------------------------------------------------------
// KA2: combine psum chunks -> rcp -> v3T[b][c][n] = y3[n][c]/sumexp[n].
// ---------------------------------------------------------------------------
__global__ __launch_bounds__(256) void kA2_v3(
    const float* __restrict__ psum, const unsigned short* __restrict__ y3t,
    unsigned short* __restrict__ v3T)
{
    const int b  = blockIdx.x >> 6;
    const int n0 = (blockIdx.x & 63) * 64;
    __shared__ float rsum[64];
    const int t = threadIdx.x;
    if (t < 64) {
        size_t idx = (size_t)b * kN + n0 + t;
        float s = psum[idx];
        #pragma unroll
        for (int ch = 1; ch < kMCH; ++ch) s += psum[(size_t)ch * kRowsT + idx];
        rsum[t] = fast_rcp(s);
    }
    __syncthreads();

    const int c = t >> 3, q = t & 7;
    float rin[8];
    #pragma unroll
    for (int u = 0; u < 8; ++u) rin[u] = rsum[q * 8 + u];
    unsigned int wds[4];
    #pragma unroll
    for (int u = 0; u < 4; ++u) {
        float a0 = bf2f(y3t[(size_t)(b * kN + n0 + q * 8 + 2 * u) * kCi + c]) * rin[2 * u];
        float a1 = bf2f(y3t[(size_t)(b * kN + n0 + q * 8 + 2 * u + 1) * kCi + c]) * rin[2 * u + 1];
        wds[u] = (unsigned)f2bf(a0) | ((unsigned)f2bf(a1) << 16);
    }
    *(uint4*)(v3T + ((size_t)(b * kCi + c) * kN + n0 + q * 8)) =
        make_uint4(wds[0], wds[1], wds[2], wds[3]);
}

// ---------------------------------------------------------------------------
// KB: PV pass, n-chunked, LDS-free, software-pipelined. 1-D grid 2048,
// id&7 = batch (XCD L2). S-tile0 = even n-rows, S-tile1 = odd n-rows;
// cvt_pk interleaves them in-lane into the PV B-fragment. Next iteration's
// four fragments are prefetched into registers before this iteration's
// compute so L2 latency hides under the MFMA->exp2->cvt->MFMA chain.
// ---------------------------------------------------------------------------
__global__ __launch_bounds__(256) void kB_pv(
    const unsigned short* __restrict__ y1t, const unsigned short* __restrict__ y2t,
    const unsigned short* __restrict__ v3T, float* __restrict__ pacc)
{
    const int l   = threadIdx.x & 63;
    const int w   = threadIdx.x >> 6;
    const int id  = blockIdx.x;
    const int b   = id & 7;
    const int jj  = id >> 3;          // 0..255
    const int mt  = jj & 63;          // m-tile
    const int nch = jj >> 6;          // n-chunk 0..3
    const int m0  = mt * 64 + w * 16;
    const int n0c = nch * (kN / kNCH);
    const int r16 = l & 15, g = l >> 4;

    const short8 B1 = *(const short8*)(
        y1t + ((size_t)(b * kN + m0 + r16) * kCi + g * 8));
    // A-frag row r16 -> even n (tile0) / odd n (tile1) of each 32-n chunk
    const unsigned short* y2e =
        y2t + ((size_t)b * kN + n0c + 2 * r16) * kCi + g * 8;
    const unsigned short* y2o = y2e + kCi;
    const unsigned short* v3b =
        v3T + ((size_t)(b * kCi) + r16) * kN + n0c + g * 8;

    f32x4 acc0 = {0.f, 0.f, 0.f, 0.f};   // c = 4g+j
    f32x4 acc1 = {0.f, 0.f, 0.f, 0.f};   // c = 16+4g+j
    const f32x4 z = {0.f, 0.f, 0.f, 0.f};

    constexpr int NT = kN / kNCH / 32;   // 32 n-steps

    // prologue: stage 0 fragments
    short8 A2a = *(const short8*)(y2e);
    short8 A2b = *(const short8*)(y2o);
    short8 A3a = *(const short8*)(v3b);
    short8 A3b = *(const short8*)(v3b + 16 * (size_t)kN);

    #pragma unroll 2
    for (int nt = 0; nt < NT; ++nt) {
        // prefetch nt+1 (clamped) while computing nt
        const size_t nbn = (size_t)((nt + 1 < NT) ? nt + 1 : nt) * 32;
        short8 nA2a = *(const short8*)(y2e + nbn * kCi);
        short8 nA2b = *(const short8*)(y2o + nbn * kCi);
        short8 nA3a = *(const short8*)(v3b + nbn);
        short8 nA3b = *(const short8*)(v3b + 16 * (size_t)kN + nbn);

        // S0 row r -> n = nb+2r ; S1 row r -> n = nb+2r+1 (cols = m0+r16..)
        f32x4 S0 = __builtin_amdgcn_mfma_f32_16x16x32_bf16(A2a, B1, z, 0, 0, 0);
        f32x4 S1 = __builtin_amdgcn_mfma_f32_16x16x32_bf16(A2b, B1, z, 0, 0, 0);

        // B-frag word j = {P(nb+8g+2j), P(nb+8g+2j+1)} = {2^S0[j], 2^S1[j]}
        union { unsigned int u[4]; short8 s; } bp;
        bp.u[0] = cvt_pk_bf16(fast_exp2(S0[0]), fast_exp2(S1[0]));
        bp.u[1] = cvt_pk_bf16(fast_exp2(S0[1]), fast_exp2(S1[1]));
        bp.u[2] = cvt_pk_bf16(fast_exp2(S0[2]), fast_exp2(S1[2]));
        bp.u[3] = cvt_pk_bf16(fast_exp2(S0[3]), fast_exp2(S1[3]));

        acc0 = __builtin_amdgcn_mfma_f32_16x16x32_bf16(A3a, bp.s, acc0, 0, 0, 0);
        acc1 = __builtin_amdgcn_mfma_f32_16x16x32_bf16(A3b, bp.s, acc1, 0, 0, 0);

        A2a = nA2a; A2b = nA2b; A3a = nA3a; A3b = nA3b;
    }

    float* outp = pacc + ((size_t)nch * kRowsT + (size_t)(b * kN) + m0 + r16) * kCi
                + 4 * g;
    *(float4*)(outp)      = make_float4(acc0[0], acc0[1], acc0[2], acc0[3]);
    *(float4*)(outp + 16) = make_float4(acc1[0], acc1[1], acc1[2], acc1[3]);
}

// ---------------------------------------------------------------------------
// KB2: sum the kNCH partial accumulators -> bf16 ylt rows.
// ---------------------------------------------------------------------------
__global__ __launch_bounds__(256) void kB2_reduce(
    const float* __restrict__ pacc, unsigned short* __restrict__ yltb)
{
    const size_t i = (size_t)blockIdx.x * 256 + threadIdx.x;   // float4 index
    const float4* src = reinterpret_cast<const float4*>(pacc);
    float4 s = src[i];
    #pragma unroll
    for (int ch = 1; ch < kNCH; ++ch) {
        float4 v = src[(size_t)ch * ((size_t)kRowsT * kCi / 4) + i];
        s.x += v.x; s.y += v.y; s.z += v.z; s.w += v.w;
    }
    uint2 o;
    o.x = (unsigned)f2bf(s.x) | ((unsigned)f2bf(s.y) << 16);
    o.y = (unsigned)f2bf(s.z) | ((unsigned)f2bf(s.w) << 16);
    *(uint2*)(yltb + 4 * i) = o;
}

// ---------------------------------------------------------------------------
// K4: final conv (32->256) + SiLU + residual. Wave = 16 px x 64 oc.
// ---------------------------------------------------------------------------
__global__ __launch_bounds__(256) void k4_mfma(
    const unsigned short* __restrict__ ylt, const short8* __restrict__ w4f,
    const float* __restrict__ b4, const float* __restrict__ x,
    float* __restrict__ out)
{
    const int l  = threadIdx.x & 63;
    const int w  = threadIdx.x >> 6;
    const int b  = blockIdx.x >> 8;
    const int n0 = (blockIdx.x & 255) * 16;
    const int px = l & 15, g = l >> 4;

    const short8 Bf = *(const short8*)(
        ylt + ((size_t)(b * kN) + n0 + px) * kCi + g * 8);

    f32x4 acc[4];
    #pragma unroll
    for (int u = 0; u < 4; ++u) {
        f32x4 z = {0.f, 0.f, 0.f, 0.f};
        acc[u] = __builtin_amdgcn_mfma_f32_16x16x32_bf16(
            w4f[(w * 4 + u) * 64 + l], Bf, z, 0, 0, 0);
    }

    const size_t pxg = (size_t)b * kC * kN + n0 + px;   // + oc*kN
    #pragma unroll
    for (int u = 0; u < 4; ++u) {
        const int oc0 = (w * 4 + u) * 16 + 4 * g;
        float4 bb = *(const float4*)(b4 + oc0);
        const float bbv[4] = {bb.x, bb.y, bb.z, bb.w};
        #pragma unroll
        for (int j = 0; j < 4; ++j) {
            const size_t idx = pxg + (size_t)(oc0 + j) * kN;
            float t = acc[u][j] + bbv[j];
            out[idx] = silu(t) + x[idx];
        }
    }
}

// ---------------------------------------------------------------------------
extern "C" void kernel_launch(void* const* d_in, const int* in_sizes, int n_in,
                              void* d_out, int out_size, void* d_ws, size_t ws_size,
                              hipStream_t stream)
{
    (void)in_sizes; (void)n_in; (void)out_size; (void)ws_size;
    const float* x  = (const float*)d_in[0];
    const float* w1 = (const float*)d_in[1];
    const float* s1 = (const float*)d_in[2];
    const float* b1 = (const float*)d_in[3];
    const float* w2 = (const float*)d_in[4];
    const float* s2 = (const float*)d_in[5];
    const float* b2 = (const float*)d_in[6];
    const float* w3 = (const float*)d_in[7];
    const float* s3 = (const float*)d_in[8];
    const float* b3 = (const float*)d_in[9];
    const float* w4 = (const float*)d_in[10];
    const float* s4 = (const float*)d_in[11];
    const float* b4 = (const float*)d_in[12];
    float* out = (float*)d_out;

    unsigned char* ws = (unsigned char*)d_ws;
    size_t off = 0;
    unsigned short* y1t = (unsigned short*)(ws + off); off += (size_t)kRowsT * kCi * 2;
    unsigned short* y2t = (unsigned short*)(ws + off); off += (size_t)kRowsT * kCi * 2;
    unsigned short* y3t = (unsigned short*)(ws + off); off += (size_t)kRowsT * kCi * 2;
    unsigned short* v3T = (unsigned short*)(ws + off); off += (size_t)kRowsT * kCi * 2;
    unsigned short* yltb= (unsigned short*)(ws + off); off += (size_t)kRowsT * kCi * 2;
    short8* wfA = (short8*)(ws + off); off += 48 * 64 * sizeof(short8);
    short8* w4f = (short8*)(ws + off); off += 16 * 64 * sizeof(short8);
    float* psum = (float*)(ws + off); off += (size_t)kMCH * kRowsT * 4;
    float* pacc = (float*)(ws + off); off += (size_t)kNCH * kRowsT * kCi * 4;

    k0_pack<<<dim3(64), dim3(64), 0, stream>>>(
        w1, s1, w2, s2, w3, s3, w4, s4, wfA, w4f);
    k1_mfma<<<dim3(kRowsT / 64), dim3(256), 0, stream>>>(
        x, wfA, b1, b2, b3, y1t, y2t, y3t);
    kA_stats<<<dim3(kBt * (kN / 64) * kMCH), dim3(256), 0, stream>>>(
        y1t, y2t, psum);                          // 2048 blocks
    kA2_v3<<<dim3(kBt * (kN / 64)), dim3(256), 0, stream>>>(psum, y3t, v3T);
    kB_pv<<<dim3(kBt * (kN / 64) * kNCH), dim3(256), 0, stream>>>(
        y1t, y2t, v3T, pacc);                     // 2048 blocks
    kB2_reduce<<<dim3((kRowsT * kCi / 4) / 256), dim3(256), 0, stream>>>(
        pacc, yltb);
    k4_mfma<<<dim3(kRowsT / 16), dim3(256), 0, stream>>>(
        yltb, w4f, b4, x, out);
}

// Round 12
// 181.078 us; speedup vs baseline: 1.5368x; 1.5216x over previous
//
#include <hip/hip_runtime.h>
#include <hip/hip_bf16.h>
#include <cstddef>
#include <cstdint>

// NonLocal block, MI355X. Round 12: kill the redundant-load MSHR bottleneck.
// All 4 waves of a kA/kB block were loading byte-identical fragments from
// global (256 line-requests per block-iteration through one CU). Now each
// block stages the shared tile ONCE into padded LDS (reg-staged, double-
// buffered, 80B rows -> 2-way bank aliasing = free), with the next tile's
// global load issued before the current tile's compute (T14 split).

namespace {
constexpr int kBt  = 8;
constexpr int kC   = 256;
constexpr int kCi  = 32;
constexpr int kN   = 4096;           // H*W
constexpr int kRowsT = kBt * kN;     // 32768
constexpr int kMCH = 4;              // m-chunks in kA
constexpr int kNCH = 4;              // n-chunks in kB
constexpr float kLog2e = 1.4426950408889634f;

typedef __attribute__((ext_vector_type(8))) short short8;
typedef __attribute__((ext_vector_type(4))) float f32x4;
}

__device__ __forceinline__ float fast_exp2(float x) { return __builtin_amdgcn_exp2f(x); }
__device__ __forceinline__ float fast_rcp(float x)  { return __builtin_amdgcn_rcpf(x); }
__device__ __forceinline__ float silu(float t) {
    return t * fast_rcp(1.f + fast_exp2(-t * kLog2e));
}
__device__ __forceinline__ unsigned short f2bf(float f) {
    union { float f; uint32_t u; } v; v.f = f;
    return (unsigned short)((v.u + 0x7FFFu + ((v.u >> 16) & 1u)) >> 16);
}
__device__ __forceinline__ float bf2f(unsigned short u) {
    union { uint32_t u; float f; } v; v.u = ((uint32_t)u) << 16;
    return v.f;
}
// packed bf16 convert: lo = src0, hi = src1 (single VOP3)
__device__ __forceinline__ unsigned int cvt_pk_bf16(float lo, float hi) {
    unsigned int r;
    asm("v_cvt_pk_bf16_f32 %0, %1, %2" : "=v"(r) : "v"(lo), "v"(hi));
    return r;
}

// ---------------------------------------------------------------------------
// K0: pack weights into MFMA A-fragment order (scale folded in).
// ---------------------------------------------------------------------------
__global__ __launch_bounds__(64) void k0_pack(
    const float* __restrict__ w1, const float* __restrict__ s1,
    const float* __restrict__ w2, const float* __restrict__ s2,
    const float* __restrict__ w3, const float* __restrict__ s3,
    const float* __restrict__ w4, const float* __restrict__ s4,
    short8* __restrict__ wfA, short8* __restrict__ w4f)
{
    const int l = threadIdx.x;
    const int bid = blockIdx.x;
    short8 v;
    if (bid < 48) {
        int ot = bid >> 3, kt = bid & 7;
        int p  = ot >> 1;
        int ocp = (ot & 1) * 16 + (l & 15);
        int k0  = kt * 32 + (l >> 4) * 8;
        const float* wp = (p == 0) ? w1 : (p == 1) ? w2 : w3;
        const float* sp = (p == 0) ? s1 : (p == 1) ? s2 : s3;
        float s = sp[ocp];
        #pragma unroll
        for (int e = 0; e < 8; ++e)
            v[e] = (short)f2bf(wp[ocp * kC + k0 + e] * s);
        wfA[bid * 64 + l] = v;
    } else {
        int ot = bid - 48;
        int oc = ot * 16 + (l & 15);
        int k0 = (l >> 4) * 8;
        float s = s4[oc];
        #pragma unroll
        for (int e = 0; e < 8; ++e)
            v[e] = (short)f2bf(w4[oc * kCi + k0 + e] * s);
        w4f[ot * 64 + l] = v;
    }
}

// ---------------------------------------------------------------------------
// K1: projections via MFMA (unchanged, validated).
// ---------------------------------------------------------------------------
__global__ __launch_bounds__(256) void k1_mfma(
    const float* __restrict__ x, const short8* __restrict__ wfA,
    const float* __restrict__ b1, const float* __restrict__ b2,
    const float* __restrict__ b3,
    unsigned short* __restrict__ y1t, unsigned short* __restrict__ y2t,
    unsigned short* __restrict__ y3t)
{
    const int l  = threadIdx.x & 63;
    const int w  = threadIdx.x >> 6;
    const int b  = blockIdx.x >> 6;
    const int n0 = (blockIdx.x & 63) * 64 + w * 16;
    const int px = l & 15, g = l >> 4;

    const float* xb = x + (size_t)b * kC * kN + n0 + px;

    f32x4 acc[6];
    #pragma unroll
    for (int ot = 0; ot < 6; ++ot) acc[ot] = (f32x4){0.f, 0.f, 0.f, 0.f};

    #pragma unroll
    for (int kt = 0; kt < 8; ++kt) {
        const float* xc = xb + (size_t)(kt * 32 + g * 8) * kN;
        float f[8];
        #pragma unroll
        for (int e = 0; e < 8; ++e) f[e] = xc[(size_t)e * kN];
        short8 Bf;
        #pragma unroll
        for (int e = 0; e < 8; ++e) Bf[e] = (short)f2bf(f[e]);
        #pragma unroll
        for (int ot = 0; ot < 6; ++ot)
            acc[ot] = __builtin_amdgcn_mfma_f32_16x16x32_bf16(
                wfA[(ot * 8 + kt) * 64 + l], Bf, acc[ot], 0, 0, 0);
    }

    const size_t rowbase = ((size_t)(b * kN) + n0 + px) * kCi;
    #pragma unroll
    for (int pp = 0; pp < 3; ++pp) {
        const float* bp = (pp == 0) ? b1 : (pp == 1) ? b2 : b3;
        unsigned short* yp = (pp == 0) ? y1t : (pp == 1) ? y2t : y3t;
        const float mul = (pp == 1) ? kLog2e : 1.0f;
        #pragma unroll
        for (int h = 0; h < 2; ++h) {
            int ot = pp * 2 + h;
            int oc0 = h * 16 + 4 * g;
            unsigned int wd[2];
            #pragma unroll
            for (int j2 = 0; j2 < 2; ++j2) {
                float v0 = silu(acc[ot][2 * j2]     + bp[oc0 + 2 * j2])     * mul;
                float v1 = silu(acc[ot][2 * j2 + 1] + bp[oc0 + 2 * j2 + 1]) * mul;
                wd[j2] = (unsigned)f2bf(v0) | ((unsigned)f2bf(v1) << 16);
            }
            *(uint2*)(yp + rowbase + oc0) = make_uint2(wd[0], wd[1]);
        }
    }
}

// ---------------------------------------------------------------------------
// KA: partial softmax denominators, LDS-staged. 1-D grid 2048, id&7 = batch.
// Block stages 64 y1 rows (4 m-steps) per round into [64][80B] padded LDS,
// double-buffered; each wave reads its B-frags from LDS (2-way = free).
// ---------------------------------------------------------------------------
__global__ __launch_bounds__(256) void kA_stats(
    const unsigned short* __restrict__ y1t, const unsigned short* __restrict__ y2t,
    float* __restrict__ psum)
{
    __shared__ __align__(16) unsigned char lbuf[2][5120];   // [64 rows][80B]
    const int t   = threadIdx.x;
    const int l   = t & 63;
    const int w   = __builtin_amdgcn_readfirstlane(t >> 6);
    const int id  = blockIdx.x;
    const int b   = id & 7;
    const int jj  = id >> 3;          // 0..255
    const int n0  = (jj & 63) * 64;   // n-tile
    const int mch = jj >> 6;          // m-chunk 0..3
    const int m0  = mch * (kN / kMCH);
    const int r16 = l & 15, g = l >> 4;

    const short8 Af = *(const short8*)(
        y2t + ((size_t)(b * kN + n0 + w * 16 + r16) * kCi + g * 8));

    // staging map: thread t -> y1 row m0+row, 16B chunk ck
    const int srow = t >> 2, sck = t & 3;
    const unsigned short* sgp =
        y1t + ((size_t)(b * kN + m0) + srow) * kCi + sck * 8;
    const int sdst = srow * 80 + sck * 16;
    const size_t sstep = (size_t)64 * kCi;        // 64 rows per outer step

    constexpr int NOUT = kN / kMCH / 64;          // 16 outer steps
    const f32x4 z = {0.f, 0.f, 0.f, 0.f};

    uint4 stg = *(const uint4*)(sgp);
    *(uint4*)(&lbuf[0][sdst]) = stg;
    stg = *(const uint4*)(sgp + sstep);
    __syncthreads();

    float s0 = 0.f, s1 = 0.f, s2 = 0.f, s3 = 0.f;
    int cur = 0;
    for (int ot = 0; ot < NOUT; ++ot) {
        #pragma unroll
        for (int ms = 0; ms < 4; ++ms) {
            short8 Bf = *(const short8*)(&lbuf[cur][(ms * 16 + r16) * 80 + g * 16]);
            f32x4 S = __builtin_amdgcn_mfma_f32_16x16x32_bf16(Af, Bf, z, 0, 0, 0);
            s0 += fast_exp2(S[0]);
            s1 += fast_exp2(S[1]);
            s2 += fast_exp2(S[2]);
            s3 += fast_exp2(S[3]);
        }
        if (ot + 1 < NOUT) {
            *(uint4*)(&lbuf[cur ^ 1][sdst]) = stg;
            if (ot + 2 < NOUT) stg = *(const uint4*)(sgp + (size_t)(ot + 2) * sstep);
        }
        __syncthreads();
        cur ^= 1;
    }

    #pragma unroll
    for (int d = 1; d < 16; d <<= 1) {
        s0 += __shfl_xor(s0, d);
        s1 += __shfl_xor(s1, d);
        s2 += __shfl_xor(s2, d);
        s3 += __shfl_xor(s3, d);
    }
    if (r16 == 0) {
        float* dst = psum + (size_t)mch * kRowsT + (size_t)b * kN
                   + n0 + w * 16 + 4 * g;
        dst[0] = s0; dst[1] = s1; dst[2] = s2; dst[3] = s3;
    }
}

// ---------------------------------------------------------------------------
// KA2: combine psum chunks -> rcp -> v3T[b][c][n] = y3[n][c]/sumexp[n].
// ---------------------------------------------------------------------------
__global__ __launch_bounds__(256) void kA2_v3(
    const float* __restrict__ psum, const unsigned short* __restrict__ y3t,
    unsigned short* __restrict__ v3T)
{
    const int b  = blockIdx.x >> 6;
    const int n0 = (blockIdx.x & 63) * 64;
    __shared__ float rsum[64];
    const int t = threadIdx.x;
    if (t < 64) {
        size_t idx = (size_t)b * kN + n0 + t;
        float s = psum[idx];
        #pragma unroll
        for (int ch = 1; ch < kMCH; ++ch) s += psum[(size_t)ch * kRowsT + idx];
        rsum[t] = fast_rcp(s);
    }
    __syncthreads();

    const int c = t >> 3, q = t & 7;
    float rin[8];
    #pragma unroll
    for (int u = 0; u < 8; ++u) rin[u] = rsum[q * 8 + u];
    unsigned int wds[4];
    #pragma unroll
    for (int u = 0; u < 4; ++u) {
        float a0 = bf2f(y3t[(size_t)(b * kN + n0 + q * 8 + 2 * u) * kCi + c]) * rin[2 * u];
        float a1 = bf2f(y3t[(size_t)(b * kN + n0 + q * 8 + 2 * u + 1) * kCi + c]) * rin[2 * u + 1];
        wds[u] = (unsigned)f2bf(a0) | ((unsigned)f2bf(a1) << 16);
    }
    *(uint4*)(v3T + ((size_t)(b * kCi + c) * kN + n0 + q * 8)) =
        make_uint4(wds[0], wds[1], wds[2], wds[3]);
}

// ---------------------------------------------------------------------------
// KB: PV pass, LDS-staged, double-buffered. 1-D grid 2048, id&7 = batch.
// Per 32-n step the block stages: Y2 parity-split [2][16 rows][80B] (even/odd
// n interleave for the in-lane cvt_pk B-frag build) + V3 [32 c][80B]. All
// waves read shared frags from LDS; next step's 4KB is in flight meanwhile.
// ---------------------------------------------------------------------------
__global__ __launch_bounds__(256) void kB_pv(
    const unsigned short* __restrict__ y1t, const unsigned short* __restrict__ y2t,
    const unsigned short* __restrict__ v3T, float* __restrict__ pacc)
{
    __shared__ __align__(16) unsigned char lbuf[2][5120];
    // buf layout: Y2 even rows [16][80] at 0; Y2 odd rows [16][80] at 1280;
    //             V3 [32 c][80] at 2560.
    const int t   = threadIdx.x;
    const int l   = t & 63;
    const int w   = t >> 6;
    const int id  = blockIdx.x;
    const int b   = id & 7;
    const int jj  = id >> 3;          // 0..255
    const int mt  = jj & 63;          // m-tile
    const int nch = jj >> 6;          // n-chunk 0..3
    const int m0  = mt * 64 + w * 16;
    const int n0c = nch * (kN / kNCH);
    const int r16 = l & 15, g = l >> 4;

    const short8 B1 = *(const short8*)(
        y1t + ((size_t)(b * kN + m0 + r16) * kCi + g * 8));

    // staging map: threads 0-127 stage the 32 y2 rows (parity-split dest),
    // threads 128-255 stage the 32 v3 c-rows.
    const unsigned short* sgp; int sdst; size_t sstep;
    if (t < 128) {
        int nl = t >> 2, ck = t & 3;                    // n-local 0..31
        sgp  = y2t + ((size_t)(b * kN + n0c) + nl) * kCi + ck * 8;
        sdst = (nl & 1) * 1280 + (nl >> 1) * 80 + ck * 16;
        sstep = (size_t)32 * kCi;
    } else {
        int tt = t - 128, c = tt >> 2, ck = tt & 3;
        sgp  = v3T + ((size_t)(b * kCi + c)) * kN + n0c + ck * 8;
        sdst = 2560 + c * 80 + ck * 16;
        sstep = 32;
    }

    f32x4 acc0 = {0.f, 0.f, 0.f, 0.f};   // c = 4g+j
    f32x4 acc1 = {0.f, 0.f, 0.f, 0.f};   // c = 16+4g+j
    const f32x4 z = {0.f, 0.f, 0.f, 0.f};

    constexpr int NT = kN / kNCH / 32;   // 32 n-steps

    uint4 stg = *(const uint4*)(sgp);
    *(uint4*)(&lbuf[0][sdst]) = stg;
    stg = *(const uint4*)(sgp + sstep);
    __syncthreads();

    int cur = 0;
    for (int nt = 0; nt < NT; ++nt) {
        // fragments from LDS (80B rows -> 2-way bank aliasing, free)
        short8 A2a = *(const short8*)(&lbuf[cur][r16 * 80 + g * 16]);          // even n
        short8 A2b = *(const short8*)(&lbuf[cur][1280 + r16 * 80 + g * 16]);   // odd n
        short8 A3a = *(const short8*)(&lbuf[cur][2560 + r16 * 80 + g * 16]);        // c 0..15
        short8 A3b = *(const short8*)(&lbuf[cur][2560 + (16 + r16) * 80 + g * 16]); // c 16..31

        // S0 row r -> n = nb+2r ; S1 row r -> n = nb+2r+1 (cols = m0+r16..)
        f32x4 S0 = __builtin_amdgcn_mfma_f32_16x16x32_bf16(A2a, B1, z, 0, 0, 0);
        f32x4 S1 = __builtin_amdgcn_mfma_f32_16x16x32_bf16(A2b, B1, z, 0, 0, 0);

        // B-frag word j = {P(nb+8g+2j), P(nb+8g+2j+1)} = {2^S0[j], 2^S1[j]}
        union { unsigned int u[4]; short8 s; } bp;
        bp.u[0] = cvt_pk_bf16(fast_exp2(S0[0]), fast_exp2(S1[0]));
        bp.u[1] = cvt_pk_bf16(fast_exp2(S0[1]), fast_exp2(S1[1]));
        bp.u[2] = cvt_pk_bf16(fast_exp2(S0[2]), fast_exp2(S1[2]));
        bp.u[3] = cvt_pk_bf16(fast_exp2(S0[3]), fast_exp2(S1[3]));

        acc0 = __builtin_amdgcn_mfma_f32_16x16x32_bf16(A3a, bp.s, acc0, 0, 0, 0);
        acc1 = __builtin_amdgcn_mfma_f32_16x16x32_bf16(A3b, bp.s, acc1, 0, 0, 0);

        if (nt + 1 < NT) {
            *(uint4*)(&lbuf[cur ^ 1][sdst]) = stg;    // write prefetched tile
            if (nt + 2 < NT) stg = *(const uint4*)(sgp + (size_t)(nt + 2) * sstep);
        }
        __syncthreads();
        cur ^= 1;
    }

    float* outp = pacc + ((size_t)nch * kRowsT + (size_t)(b * kN) + m0 + r16) * kCi
                + 4 * g;
    *(float4*)(outp)      = make_float4(acc0[0], acc0[1], acc0[2], acc0[3]);
    *(float4*)(outp + 16) = make_float4(acc1[0], acc1[1], acc1[2], acc1[3]);
}

// ---------------------------------------------------------------------------
// KB2: sum the kNCH partial accumulators -> bf16 ylt rows.
// ---------------------------------------------------------------------------
__global__ __launch_bounds__(256) void kB2_reduce(
    const float* __restrict__ pacc, unsigned short* __restrict__ yltb)
{
    const size_t i = (size_t)blockIdx.x * 256 + threadIdx.x;   // float4 index
    const float4* src = reinterpret_cast<const float4*>(pacc);
    float4 s = src[i];
    #pragma unroll
    for (int ch = 1; ch < kNCH; ++ch) {
        float4 v = src[(size_t)ch * ((size_t)kRowsT * kCi / 4) + i];
        s.x += v.x; s.y += v.y; s.z += v.z; s.w += v.w;
    }
    uint2 o;
    o.x = (unsigned)f2bf(s.x) | ((unsigned)f2bf(s.y) << 16);
    o.y = (unsigned)f2bf(s.z) | ((unsigned)f2bf(s.w) << 16);
    *(uint2*)(yltb + 4 * i) = o;
}

// ---------------------------------------------------------------------------
// K4: final conv (32->256) + SiLU + residual. Wave = 16 px x 64 oc.
// ---------------------------------------------------------------------------
__global__ __launch_bounds__(256) void k4_mfma(
    const unsigned short* __restrict__ ylt, const short8* __restrict__ w4f,
    const float* __restrict__ b4, const float* __restrict__ x,
    float* __restrict__ out)
{
    const int l  = threadIdx.x & 63;
    const int w  = threadIdx.x >> 6;
    const int b  = blockIdx.x >> 8;
    const int n0 = (blockIdx.x & 255) * 16;
    const int px = l & 15, g = l >> 4;

    const short8 Bf = *(const short8*)(
        ylt + ((size_t)(b * kN) + n0 + px) * kCi + g * 8);

    f32x4 acc[4];
    #pragma unroll
    for (int u = 0; u < 4; ++u) {
        f32x4 z = {0.f, 0.f, 0.f, 0.f};
        acc[u] = __builtin_amdgcn_mfma_f32_16x16x32_bf16(
            w4f[(w * 4 + u) * 64 + l], Bf, z, 0, 0, 0);
    }

    const size_t pxg = (size_t)b * kC * kN + n0 + px;   // + oc*kN
    #pragma unroll
    for (int u = 0; u < 4; ++u) {
        const int oc0 = (w * 4 + u) * 16 + 4 * g;
        float4 bb = *(const float4*)(b4 + oc0);
        const float bbv[4] = {bb.x, bb.y, bb.z, bb.w};
        #pragma unroll
        for (int j = 0; j < 4; ++j) {
            const size_t idx = pxg + (size_t)(oc0 + j) * kN;
            float t = acc[u][j] + bbv[j];
            out[idx] = silu(t) + x[idx];
        }
    }
}

// ---------------------------------------------------------------------------
extern "C" void kernel_launch(void* const* d_in, const int* in_sizes, int n_in,
                              void* d_out, int out_size, void* d_ws, size_t ws_size,
                              hipStream_t stream)
{
    (void)in_sizes; (void)n_in; (void)out_size; (void)ws_size;
    const float* x  = (const float*)d_in[0];
    const float* w1 = (const float*)d_in[1];
    const float* s1 = (const float*)d_in[2];
    const float* b1 = (const float*)d_in[3];
    const float* w2 = (const float*)d_in[4];
    const float* s2 = (const float*)d_in[5];
    const float* b2 = (const float*)d_in[6];
    const float* w3 = (const float*)d_in[7];
    const float* s3 = (const float*)d_in[8];
    const float* b3 = (const float*)d_in[9];
    const float* w4 = (const float*)d_in[10];
    const float* s4 = (const float*)d_in[11];
    const float* b4 = (const float*)d_in[12];
    float* out = (float*)d_out;

    unsigned char* ws = (unsigned char*)d_ws;
    size_t off = 0;
    unsigned short* y1t = (unsigned short*)(ws + off); off += (size_t)kRowsT * kCi * 2;
    unsigned short* y2t = (unsigned short*)(ws + off); off += (size_t)kRowsT * kCi * 2;
    unsigned short* y3t = (unsigned short*)(ws + off); off += (size_t)kRowsT * kCi * 2;
    unsigned short* v3T = (unsigned short*)(ws + off); off += (size_t)kRowsT * kCi * 2;
    unsigned short* yltb= (unsigned short*)(ws + off); off += (size_t)kRowsT * kCi * 2;
    short8* wfA = (short8*)(ws + off); off += 48 * 64 * sizeof(short8);
    short8* w4f = (short8*)(ws + off); off += 16 * 64 * sizeof(short8);
    float* psum = (float*)(ws + off); off += (size_t)kMCH * kRowsT * 4;
    float* pacc = (float*)(ws + off); off += (size_t)kNCH * kRowsT * kCi * 4;

    k0_pack<<<dim3(64), dim3(64), 0, stream>>>(
        w1, s1, w2, s2, w3, s3, w4, s4, wfA, w4f);
    k1_mfma<<<dim3(kRowsT / 64), dim3(256), 0, stream>>>(
        x, wfA, b1, b2, b3, y1t, y2t, y3t);
    kA_stats<<<dim3(kBt * (kN / 64) * kMCH), dim3(256), 0, stream>>>(
        y1t, y2t, psum);                          // 2048 blocks
    kA2_v3<<<dim3(kBt * (kN / 64)), dim3(256), 0, stream>>>(psum, y3t, v3T);
    kB_pv<<<dim3(kBt * (kN / 64) * kNCH), dim3(256), 0, stream>>>(
        y1t, y2t, v3T, pacc);                     // 2048 blocks
    kB2_reduce<<<dim3((kRowsT * kCi / 4) / 256), dim3(256), 0, stream>>>(
        pacc, yltb);
    k4_mfma<<<dim3(kRowsT / 16), dim3(256), 0, stream>>>(
        yltb, w4f, b4, x, out);
}

// Round 13
// 177.569 us; speedup vs baseline: 1.5671x; 1.0198x over previous
//
#include <hip/hip_runtime.h>
#include <hip/hip_bf16.h>
#include <cstddef>
#include <cstdint>

// NonLocal block, MI355X. Round 13: deepen kA/kB stages (halve barriers).
// kB: 64-n stages (8 MFMA + 16 exp2 per barrier), double-buffered LDS
//     {Y2 parity-split [2][32][80B], V3 [32][144B]}, 32B/thread staging.
// kA: 128-row stages (8 MFMA per barrier), [128][80B] x2, 32B/thread.
// Fragment math identical to validated round-12 kernel.

namespace {
constexpr int kBt  = 8;
constexpr int kC   = 256;
constexpr int kCi  = 32;
constexpr int kN   = 4096;           // H*W
constexpr int kRowsT = kBt * kN;     // 32768
constexpr int kMCH = 4;              // m-chunks in kA
constexpr int kNCH = 4;              // n-chunks in kB
constexpr float kLog2e = 1.4426950408889634f;

typedef __attribute__((ext_vector_type(8))) short short8;
typedef __attribute__((ext_vector_type(4))) float f32x4;
}

__device__ __forceinline__ float fast_exp2(float x) { return __builtin_amdgcn_exp2f(x); }
__device__ __forceinline__ float fast_rcp(float x)  { return __builtin_amdgcn_rcpf(x); }
__device__ __forceinline__ float silu(float t) {
    return t * fast_rcp(1.f + fast_exp2(-t * kLog2e));
}
__device__ __forceinline__ unsigned short f2bf(float f) {
    union { float f; uint32_t u; } v; v.f = f;
    return (unsigned short)((v.u + 0x7FFFu + ((v.u >> 16) & 1u)) >> 16);
}
__device__ __forceinline__ float bf2f(unsigned short u) {
    union { uint32_t u; float f; } v; v.u = ((uint32_t)u) << 16;
    return v.f;
}
// packed bf16 convert: lo = src0, hi = src1 (single VOP3)
__device__ __forceinline__ unsigned int cvt_pk_bf16(float lo, float hi) {
    unsigned int r;
    asm("v_cvt_pk_bf16_f32 %0, %1, %2" : "=v"(r) : "v"(lo), "v"(hi));
    return r;
}

// ---------------------------------------------------------------------------
// K0: pack weights into MFMA A-fragment order (scale folded in).
// ---------------------------------------------------------------------------
__global__ __launch_bounds__(64) void k0_pack(
    const float* __restrict__ w1, const float* __restrict__ s1,
    const float* __restrict__ w2, const float* __restrict__ s2,
    const float* __restrict__ w3, const float* __restrict__ s3,
    const float* __restrict__ w4, const float* __restrict__ s4,
    short8* __restrict__ wfA, short8* __restrict__ w4f)
{
    const int l = threadIdx.x;
    const int bid = blockIdx.x;
    short8 v;
    if (bid < 48) {
        int ot = bid >> 3, kt = bid & 7;
        int p  = ot >> 1;
        int ocp = (ot & 1) * 16 + (l & 15);
        int k0  = kt * 32 + (l >> 4) * 8;
        const float* wp = (p == 0) ? w1 : (p == 1) ? w2 : w3;
        const float* sp = (p == 0) ? s1 : (p == 1) ? s2 : s3;
        float s = sp[ocp];
        #pragma unroll
        for (int e = 0; e < 8; ++e)
            v[e] = (short)f2bf(wp[ocp * kC + k0 + e] * s);
        wfA[bid * 64 + l] = v;
    } else {
        int ot = bid - 48;
        int oc = ot * 16 + (l & 15);
        int k0 = (l >> 4) * 8;
        float s = s4[oc];
        #pragma unroll
        for (int e = 0; e < 8; ++e)
            v[e] = (short)f2bf(w4[oc * kCi + k0 + e] * s);
        w4f[ot * 64 + l] = v;
    }
}

// ---------------------------------------------------------------------------
// K1: projections via MFMA (unchanged, validated).
// ---------------------------------------------------------------------------
__global__ __launch_bounds__(256) void k1_mfma(
    const float* __restrict__ x, const short8* __restrict__ wfA,
    const float* __restrict__ b1, const float* __restrict__ b2,
    const float* __restrict__ b3,
    unsigned short* __restrict__ y1t, unsigned short* __restrict__ y2t,
    unsigned short* __restrict__ y3t)
{
    const int l  = threadIdx.x & 63;
    const int w  = threadIdx.x >> 6;
    const int b  = blockIdx.x >> 6;
    const int n0 = (blockIdx.x & 63) * 64 + w * 16;
    const int px = l & 15, g = l >> 4;

    const float* xb = x + (size_t)b * kC * kN + n0 + px;

    f32x4 acc[6];
    #pragma unroll
    for (int ot = 0; ot < 6; ++ot) acc[ot] = (f32x4){0.f, 0.f, 0.f, 0.f};

    #pragma unroll
    for (int kt = 0; kt < 8; ++kt) {
        const float* xc = xb + (size_t)(kt * 32 + g * 8) * kN;
        float f[8];
        #pragma unroll
        for (int e = 0; e < 8; ++e) f[e] = xc[(size_t)e * kN];
        short8 Bf;
        #pragma unroll
        for (int e = 0; e < 8; ++e) Bf[e] = (short)f2bf(f[e]);
        #pragma unroll
        for (int ot = 0; ot < 6; ++ot)
            acc[ot] = __builtin_amdgcn_mfma_f32_16x16x32_bf16(
                wfA[(ot * 8 + kt) * 64 + l], Bf, acc[ot], 0, 0, 0);
    }

    const size_t rowbase = ((size_t)(b * kN) + n0 + px) * kCi;
    #pragma unroll
    for (int pp = 0; pp < 3; ++pp) {
        const float* bp = (pp == 0) ? b1 : (pp == 1) ? b2 : b3;
        unsigned short* yp = (pp == 0) ? y1t : (pp == 1) ? y2t : y3t;
        const float mul = (pp == 1) ? kLog2e : 1.0f;
        #pragma unroll
        for (int h = 0; h < 2; ++h) {
            int ot = pp * 2 + h;
            int oc0 = h * 16 + 4 * g;
            unsigned int wd[2];
            #pragma unroll
            for (int j2 = 0; j2 < 2; ++j2) {
                float v0 = silu(acc[ot][2 * j2]     + bp[oc0 + 2 * j2])     * mul;
                float v1 = silu(acc[ot][2 * j2 + 1] + bp[oc0 + 2 * j2 + 1]) * mul;
                wd[j2] = (unsigned)f2bf(v0) | ((unsigned)f2bf(v1) << 16);
            }
            *(uint2*)(yp + rowbase + oc0) = make_uint2(wd[0], wd[1]);
        }
    }
}

// ---------------------------------------------------------------------------
// KA: partial softmax denominators, LDS-staged 128-row stages (8 MFMA per
// barrier). 1-D grid 2048, id&7 = batch (XCD L2).
// ---------------------------------------------------------------------------
__global__ __launch_bounds__(256) void kA_stats(
    const unsigned short* __restrict__ y1t, const unsigned short* __restrict__ y2t,
    float* __restrict__ psum)
{
    __shared__ __align__(16) unsigned char lbuf[2][10240];   // [128 rows][80B]
    const int t   = threadIdx.x;
    const int l   = t & 63;
    const int w   = __builtin_amdgcn_readfirstlane(t >> 6);
    const int id  = blockIdx.x;
    const int b   = id & 7;
    const int jj  = id >> 3;          // 0..255
    const int n0  = (jj & 63) * 64;   // n-tile
    const int mch = jj >> 6;          // m-chunk 0..3
    const int m0  = mch * (kN / kMCH);
    const int r16 = l & 15, g = l >> 4;

    const short8 Af = *(const short8*)(
        y2t + ((size_t)(b * kN + n0 + w * 16 + r16) * kCi + g * 8));

    // staging map: 2 threads per row, 32B each (whole row = 64B)
    const int srow = t >> 1, sh = t & 1;
    const unsigned short* sgp =
        y1t + ((size_t)(b * kN + m0) + srow) * kCi + sh * 16;
    const int sdst = srow * 80 + sh * 32;
    const size_t sstep = (size_t)128 * kCi;       // 128 rows per stage

    constexpr int NS = kN / kMCH / 128;           // 8 stages
    const f32x4 z = {0.f, 0.f, 0.f, 0.f};

    uint4 sa = *(const uint4*)(sgp);
    uint4 sb = *(const uint4*)(sgp + 8);
    *(uint4*)(&lbuf[0][sdst])      = sa;
    *(uint4*)(&lbuf[0][sdst + 16]) = sb;
    sa = *(const uint4*)(sgp + sstep);
    sb = *(const uint4*)(sgp + sstep + 8);
    __syncthreads();

    float s0 = 0.f, s1 = 0.f, s2 = 0.f, s3 = 0.f;
    int cur = 0;
    for (int s = 0; s < NS; ++s) {
        #pragma unroll
        for (int ms = 0; ms < 8; ++ms) {
            short8 Bf = *(const short8*)(&lbuf[cur][(ms * 16 + r16) * 80 + g * 16]);
            f32x4 S = __builtin_amdgcn_mfma_f32_16x16x32_bf16(Af, Bf, z, 0, 0, 0);
            s0 += fast_exp2(S[0]);
            s1 += fast_exp2(S[1]);
            s2 += fast_exp2(S[2]);
            s3 += fast_exp2(S[3]);
        }
        if (s + 1 < NS) {
            *(uint4*)(&lbuf[cur ^ 1][sdst])      = sa;
            *(uint4*)(&lbuf[cur ^ 1][sdst + 16]) = sb;
            if (s + 2 < NS) {
                sa = *(const uint4*)(sgp + (size_t)(s + 2) * sstep);
                sb = *(const uint4*)(sgp + (size_t)(s + 2) * sstep + 8);
            }
        }
        __syncthreads();
        cur ^= 1;
    }

    #pragma unroll
    for (int d = 1; d < 16; d <<= 1) {
        s0 += __shfl_xor(s0, d);
        s1 += __shfl_xor(s1, d);
        s2 += __shfl_xor(s2, d);
        s3 += __shfl_xor(s3, d);
    }
    if (r16 == 0) {
        float* dst = psum + (size_t)mch * kRowsT + (size_t)b * kN
                   + n0 + w * 16 + 4 * g;
        dst[0] = s0; dst[1] = s1; dst[2] = s2; dst[3] = s3;
    }
}

// ---------------------------------------------------------------------------
// KA2: combine psum chunks -> rcp -> v3T[b][c][n] = y3[n][c]/sumexp[n].
// ---------------------------------------------------------------------------
__global__ __launch_bounds__(256) void kA2_v3(
    const float* __restrict__ psum, const unsigned short* __restrict__ y3t,
    unsigned short* __restrict__ v3T)
{
    const int b  = blockIdx.x >> 6;
    const int n0 = (blockIdx.x & 63) * 64;
    __shared__ float rsum[64];
    const int t = threadIdx.x;
    if (t < 64) {
        size_t idx = (size_t)b * kN + n0 + t;
        float s = psum[idx];
        #pragma unroll
        for (int ch = 1; ch < kMCH; ++ch) s += psum[(size_t)ch * kRowsT + idx];
        rsum[t] = fast_rcp(s);
    }
    __syncthreads();

    const int c = t >> 3, q = t & 7;
    float rin[8];
    #pragma unroll
    for (int u = 0; u < 8; ++u) rin[u] = rsum[q * 8 + u];
    unsigned int wds[4];
    #pragma unroll
    for (int u = 0; u < 4; ++u) {
        float a0 = bf2f(y3t[(size_t)(b * kN + n0 + q * 8 + 2 * u) * kCi + c]) * rin[2 * u];
        float a1 = bf2f(y3t[(size_t)(b * kN + n0 + q * 8 + 2 * u + 1) * kCi + c]) * rin[2 * u + 1];
        wds[u] = (unsigned)f2bf(a0) | ((unsigned)f2bf(a1) << 16);
    }
    *(uint4*)(v3T + ((size_t)(b * kCi + c) * kN + n0 + q * 8)) =
        make_uint4(wds[0], wds[1], wds[2], wds[3]);
}

// ---------------------------------------------------------------------------
// KB: PV pass, LDS-staged 64-n stages (8 MFMA + 16 exp2 per barrier),
// double-buffered. 1-D grid 2048, id&7 = batch (XCD L2).
// Buffer layout: Y2 even rows [32][80] @0; Y2 odd rows [32][80] @2560;
//                V3 [32 c][144] @5120 (64 n x 2B + 16B pad).
// ---------------------------------------------------------------------------
__global__ __launch_bounds__(256) void kB_pv(
    const unsigned short* __restrict__ y1t, const unsigned short* __restrict__ y2t,
    const unsigned short* __restrict__ v3T, float* __restrict__ pacc)
{
    __shared__ __align__(16) unsigned char lbuf[2][9728];
    const int t   = threadIdx.x;
    const int l   = t & 63;
    const int w   = t >> 6;
    const int id  = blockIdx.x;
    const int b   = id & 7;
    const int jj  = id >> 3;          // 0..255
    const int mt  = jj & 63;          // m-tile
    const int nch = jj >> 6;          // n-chunk 0..3
    const int m0  = mt * 64 + w * 16;
    const int n0c = nch * (kN / kNCH);
    const int r16 = l & 15, g = l >> 4;

    const short8 B1 = *(const short8*)(
        y1t + ((size_t)(b * kN + m0 + r16) * kCi + g * 8));

    // staging: threads 0-127 -> 64 y2 rows (2 threads/row, parity-split dest);
    //          threads 128-255 -> 32 v3 c-rows (4 threads/row, 32B chunks).
    const unsigned short* sgp; int sdst; size_t sstep;
    if (t < 128) {
        int nl = t >> 1, h = t & 1;                     // n-local 0..63
        sgp  = y2t + ((size_t)(b * kN + n0c) + nl) * kCi + h * 16;
        sdst = (nl & 1) * 2560 + (nl >> 1) * 80 + h * 32;
        sstep = (size_t)64 * kCi;
    } else {
        int tt = t - 128, c = tt >> 2, q = tt & 3;
        sgp  = v3T + ((size_t)(b * kCi + c)) * kN + n0c + q * 16;
        sdst = 5120 + c * 144 + q * 32;
        sstep = 64;
    }

    f32x4 acc0 = {0.f, 0.f, 0.f, 0.f};   // c = 4g+j
    f32x4 acc1 = {0.f, 0.f, 0.f, 0.f};   // c = 16+4g+j
    const f32x4 z = {0.f, 0.f, 0.f, 0.f};

    constexpr int NS = kN / kNCH / 64;   // 16 stages

    uint4 sa = *(const uint4*)(sgp);
    uint4 sb = *(const uint4*)(sgp + 8);
    *(uint4*)(&lbuf[0][sdst])      = sa;
    *(uint4*)(&lbuf[0][sdst + 16]) = sb;
    sa = *(const uint4*)(sgp + sstep);
    sb = *(const uint4*)(sgp + sstep + 8);
    __syncthreads();

    int cur = 0;
    for (int s = 0; s < NS; ++s) {
        #pragma unroll
        for (int ss = 0; ss < 2; ++ss) {
            // sub-step ss covers n-local [32ss, 32ss+32)
            short8 A2a = *(const short8*)(&lbuf[cur][(ss * 16 + r16) * 80 + g * 16]);
            short8 A2b = *(const short8*)(&lbuf[cur][2560 + (ss * 16 + r16) * 80 + g * 16]);
            short8 A3a = *(const short8*)(&lbuf[cur][5120 + r16 * 144 + ss * 64 + g * 16]);
            short8 A3b = *(const short8*)(&lbuf[cur][5120 + (16 + r16) * 144 + ss * 64 + g * 16]);

            f32x4 S0 = __builtin_amdgcn_mfma_f32_16x16x32_bf16(A2a, B1, z, 0, 0, 0);
            f32x4 S1 = __builtin_amdgcn_mfma_f32_16x16x32_bf16(A2b, B1, z, 0, 0, 0);

            union { unsigned int u[4]; short8 s; } bp;
            bp.u[0] = cvt_pk_bf16(fast_exp2(S0[0]), fast_exp2(S1[0]));
            bp.u[1] = cvt_pk_bf16(fast_exp2(S0[1]), fast_exp2(S1[1]));
            bp.u[2] = cvt_pk_bf16(fast_exp2(S0[2]), fast_exp2(S1[2]));
            bp.u[3] = cvt_pk_bf16(fast_exp2(S0[3]), fast_exp2(S1[3]));

            acc0 = __builtin_amdgcn_mfma_f32_16x16x32_bf16(A3a, bp.s, acc0, 0, 0, 0);
            acc1 = __builtin_amdgcn_mfma_f32_16x16x32_bf16(A3b, bp.s, acc1, 0, 0, 0);
        }
        if (s + 1 < NS) {
            *(uint4*)(&lbuf[cur ^ 1][sdst])      = sa;
            *(uint4*)(&lbuf[cur ^ 1][sdst + 16]) = sb;
            if (s + 2 < NS) {
                sa = *(const uint4*)(sgp + (size_t)(s + 2) * sstep);
                sb = *(const uint4*)(sgp + (size_t)(s + 2) * sstep + 8);
            }
        }
        __syncthreads();
        cur ^= 1;
    }

    float* outp = pacc + ((size_t)nch * kRowsT + (size_t)(b * kN) + m0 + r16) * kCi
                + 4 * g;
    *(float4*)(outp)      = make_float4(acc0[0], acc0[1], acc0[2], acc0[3]);
    *(float4*)(outp + 16) = make_float4(acc1[0], acc1[1], acc1[2], acc1[3]);
}

// ---------------------------------------------------------------------------
// KB2: sum the kNCH partial accumulators -> bf16 ylt rows.
// ---------------------------------------------------------------------------
__global__ __launch_bounds__(256) void kB2_reduce(
    const float* __restrict__ pacc, unsigned short* __restrict__ yltb)
{
    const size_t i = (size_t)blockIdx.x * 256 + threadIdx.x;   // float4 index
    const float4* src = reinterpret_cast<const float4*>(pacc);
    float4 s = src[i];
    #pragma unroll
    for (int ch = 1; ch < kNCH; ++ch) {
        float4 v = src[(size_t)ch * ((size_t)kRowsT * kCi / 4) + i];
        s.x += v.x; s.y += v.y; s.z += v.z; s.w += v.w;
    }
    uint2 o;
    o.x = (unsigned)f2bf(s.x) | ((unsigned)f2bf(s.y) << 16);
    o.y = (unsigned)f2bf(s.z) | ((unsigned)f2bf(s.w) << 16);
    *(uint2*)(yltb + 4 * i) = o;
}

// ---------------------------------------------------------------------------
// K4: final conv (32->256) + SiLU + residual. Wave = 16 px x 64 oc.
// ---------------------------------------------------------------------------
__global__ __launch_bounds__(256) void k4_mfma(
    const unsigned short* __restrict__ ylt, const short8* __restrict__ w4f,
    const float* __restrict__ b4, const float* __restrict__ x,
    float* __restrict__ out)
{
    const int l  = threadIdx.x & 63;
    const int w  = threadIdx.x >> 6;
    const int b  = blockIdx.x >> 8;
    const int n0 = (blockIdx.x & 255) * 16;
    const int px = l & 15, g = l >> 4;

    const short8 Bf = *(const short8*)(
        ylt + ((size_t)(b * kN) + n0 + px) * kCi + g * 8);

    f32x4 acc[4];
    #pragma unroll
    for (int u = 0; u < 4; ++u) {
        f32x4 z = {0.f, 0.f, 0.f, 0.f};
        acc[u] = __builtin_amdgcn_mfma_f32_16x16x32_bf16(
            w4f[(w * 4 + u) * 64 + l], Bf, z, 0, 0, 0);
    }

    const size_t pxg = (size_t)b * kC * kN + n0 + px;   // + oc*kN
    #pragma unroll
    for (int u = 0; u < 4; ++u) {
        const int oc0 = (w * 4 + u) * 16 + 4 * g;
        float4 bb = *(const float4*)(b4 + oc0);
        const float bbv[4] = {bb.x, bb.y, bb.z, bb.w};
        #pragma unroll
        for (int j = 0; j < 4; ++j) {
            const size_t idx = pxg + (size_t)(oc0 + j) * kN;
            float t = acc[u][j] + bbv[j];
            out[idx] = silu(t) + x[idx];
        }
    }
}

// ---------------------------------------------------------------------------
extern "C" void kernel_launch(void* const* d_in, const int* in_sizes, int n_in,
                              void* d_out, int out_size, void* d_ws, size_t ws_size,
                              hipStream_t stream)
{
    (void)in_sizes; (void)n_in; (void)out_size; (void)ws_size;
    const float* x  = (const float*)d_in[0];
    const float* w1 = (const float*)d_in[1];
    const float* s1 = (const float*)d_in[2];
    const float* b1 = (const float*)d_in[3];
    const float* w2 = (const float*)d_in[4];
    const float* s2 = (const float*)d_in[5];
    const float* b2 = (const float*)d_in[6];
    const float* w3 = (const float*)d_in[7];
    const float* s3 = (const float*)d_in[8];
    const float* b3 = (const float*)d_in[9];
    const float* w4 = (const float*)d_in[10];
    const float* s4 = (const float*)d_in[11];
    const float* b4 = (const float*)d_in[12];
    float* out = (float*)d_out;

    unsigned char* ws = (unsigned char*)d_ws;
    size_t off = 0;
    unsigned short* y1t = (unsigned short*)(ws + off); off += (size_t)kRowsT * kCi * 2;
    unsigned short* y2t = (unsigned short*)(ws + off); off += (size_t)kRowsT * kCi * 2;
    unsigned short* y3t = (unsigned short*)(ws + off); off += (size_t)kRowsT * kCi * 2;
    unsigned short* v3T = (unsigned short*)(ws + off); off += (size_t)kRowsT * kCi * 2;
    unsigned short* yltb= (unsigned short*)(ws + off); off += (size_t)kRowsT * kCi * 2;
    short8* wfA = (short8*)(ws + off); off += 48 * 64 * sizeof(short8);
    short8* w4f = (short8*)(ws + off); off += 16 * 64 * sizeof(short8);
    float* psum = (float*)(ws + off); off += (size_t)kMCH * kRowsT * 4;
    float* pacc = (float*)(ws + off); off += (size_t)kNCH * kRowsT * kCi * 4;

    k0_pack<<<dim3(64), dim3(64), 0, stream>>>(
        w1, s1, w2, s2, w3, s3, w4, s4, wfA, w4f);
    k1_mfma<<<dim3(kRowsT / 64), dim3(256), 0, stream>>>(
        x, wfA, b1, b2, b3, y1t, y2t, y3t);
    kA_stats<<<dim3(kBt * (kN / 64) * kMCH), dim3(256), 0, stream>>>(
        y1t, y2t, psum);                          // 2048 blocks
    kA2_v3<<<dim3(kBt * (kN / 64)), dim3(256), 0, stream>>>(psum, y3t, v3T);
    kB_pv<<<dim3(kBt * (kN / 64) * kNCH), dim3(256), 0, stream>>>(
        y1t, y2t, v3T, pacc);                     // 2048 blocks
    kB2_reduce<<<dim3((kRowsT * kCi / 4) / 256), dim3(256), 0, stream>>>(
        pacc, yltb);
    k4_mfma<<<dim3(kRowsT / 16), dim3(256), 0, stream>>>(
        yltb, w4f, b4, x, out);
}